// Round 7
// baseline (3301.104 us; speedup 1.0000x reference)
//
#include <hip/hip_runtime.h>
#include <math.h>

// LatentSDE (L=C=D=1, H=64): every network is tabulated, including f(z,c)
// (2D, bilinear). The scan is then a pure scalar recurrence -> thread-per-b,
// no cross-lane ops at all. Tables live in GLOBAL memory (L1/L2-hot, no LDS
// staging). 6 loads/step: et2 (float2 x-pair), hgp4 (float4 h,g,p), ft2
// (float2 c-pair, z-row-major), xs, dW. OOB z/c -> exact per-lane MLP
// fallback (round-6-verified semantics). Reduction fused via atomic counter.

#define B_SZ 8192
#define T_SZ 128
#define NBLK 128                 // scan blocks (64 thr each, thread-per-b)

#define NZT 2048                 // z intervals, z in [-128,128], dz=1/8
#define ZSF 8.0f
#define ZOF 1024.0f
#define NXT 2048                 // x intervals, x in [-8,8], dx=1/128
#define XSF 128.0f
#define XOF 1024.0f
#define NCT 128                  // c intervals, c in [-4,4], dc=1/16
#define CSF 16.0f
#define COF 64.0f

// workspace layout (floats)
#define ET2_OFF 0                            // 2049 float2 = 4098, pad 4100
#define HGP_OFF 4100                         // 2049 float4 = 8196
#define FT2_OFF 12296                        // 2049*128 float2 = 524544
#define WS_FLOATS (FT2_OFF + 2049*NCT*2)     // 536840

#define NE_BUILD 2049
#define NH_BUILD 2049
#define NF_BUILD (2049*NCT)
#define NBUILD (NE_BUILD + NH_BUILD + NF_BUILD)   // 266370

#if __has_builtin(__builtin_amdgcn_rcpf)
#define RCPF(x) __builtin_amdgcn_rcpf(x)
#else
#define RCPF(x) (1.0f / (x))
#endif
#if __has_builtin(__builtin_amdgcn_sqrtf)
#define SQRTF(x) __builtin_amdgcn_sqrtf(x)
#else
#define SQRTF(x) sqrtf(x)
#endif

__device__ __forceinline__ float sp_precise(float a) {
  // stable softplus
  return fmaxf(a, 0.0f) + log1pf(expf(-fabsf(a)));
}

// ------------- single build kernel: e-pairs, hgp quads, f c-pairs -------------
__global__ __launch_bounds__(256) void build_tabs(
    const float* __restrict__ ew1, const float* __restrict__ eb1,
    const float* __restrict__ ew2, const float* __restrict__ eb2,
    const float* __restrict__ fw1, const float* __restrict__ fb1,
    const float* __restrict__ fw2, const float* __restrict__ fb2,
    const float* __restrict__ hw1, const float* __restrict__ hb1,
    const float* __restrict__ hw2, const float* __restrict__ hb2,
    const float* __restrict__ gw1, const float* __restrict__ gb1,
    const float* __restrict__ gw2, const float* __restrict__ gb2,
    const float* __restrict__ pw1, const float* __restrict__ pb1,
    const float* __restrict__ pw2, const float* __restrict__ pb2,
    float* __restrict__ tabs, int* __restrict__ ctr)
{
  const int gid = blockIdx.x * 256 + threadIdx.x;
  if (gid == 0) *ctr = 0;

  if (gid < NE_BUILD) {
    // encoder pair (e(x_i), e(x_{i+1}))
    const float x0 = -8.0f + (float)gid * (1.0f / 128.0f);
    const float x1 = x0 + (1.0f / 128.0f);
    float s0 = 0.0f, s1 = 0.0f;
    for (int j = 0; j < 64; ++j) {
      const float w = ew1[j], bb = eb1[j], w2 = ew2[j];
      s0 = fmaf(sp_precise(fmaf(x0, w, bb)), w2, s0);
      s1 = fmaf(sp_precise(fmaf(x1, w, bb)), w2, s1);
    }
    const float eb = eb2[0];
    ((float2*)(tabs + ET2_OFF))[gid] = make_float2(s0 + eb, s1 + eb);
  } else if (gid < NE_BUILD + NH_BUILD) {
    const int i = gid - NE_BUILD;
    const float z = -128.0f + (float)i * 0.125f;
    float sh = 0.0f, sg = 0.0f, sp = 0.0f;
    for (int j = 0; j < 64; ++j) {
      sh = fmaf(sp_precise(fmaf(z, hw1[j], hb1[j])), hw2[j], sh);
      sg = fmaf(sp_precise(fmaf(z, gw1[j], gb1[j])), gw2[j], sg);
      sp = fmaf(sp_precise(fmaf(z, pw1[j], pb1[j])), pw2[j], sp);
    }
    const float h = sh + hb2[0];
    const float g = 1.0f / (1.0f + expf(-(sg + gb2[0])));
    const float p = sp + pb2[0];
    ((float4*)(tabs + HGP_OFF))[i] = make_float4(h, g, p, 0.0f);
  } else if (gid < NBUILD) {
    const int fi = gid - NE_BUILD - NH_BUILD;
    const int iz = fi >> 7;            // /128
    const int ci = fi & 127;
    const float z  = -128.0f + (float)iz * 0.125f;
    const float c0 = -4.0f + (float)ci * (1.0f / 16.0f);
    const float c1 = c0 + (1.0f / 16.0f);
    float s0 = 0.0f, s1 = 0.0f;
    for (int j = 0; j < 64; ++j) {
      const float az = fmaf(z, fw1[j], fb1[j]);
      const float wc = fw1[64 + j], w2 = fw2[j];
      s0 = fmaf(sp_precise(fmaf(c0, wc, az)), w2, s0);
      s1 = fmaf(sp_precise(fmaf(c1, wc, az)), w2, s1);
    }
    const float fb = fb2[0];
    ((float2*)(tabs + FT2_OFF))[iz * NCT + ci] = make_float2(s0 + fb, s1 + fb);
  }
}

// ------------- the scan: thread-per-b, fused final reduction -------------
__global__ __launch_bounds__(64) void sde_scan(
    const float* __restrict__ xs, const float* __restrict__ ts,
    const float* __restrict__ noise_std, const float* __restrict__ eps0,
    const float* __restrict__ dW,
    const float* __restrict__ qw,  const float* __restrict__ qb,
    const float* __restrict__ fw1, const float* __restrict__ fb1,
    const float* __restrict__ fw2, const float* __restrict__ fb2,
    const float* __restrict__ hw1, const float* __restrict__ hb1,
    const float* __restrict__ hw2, const float* __restrict__ hb2,
    const float* __restrict__ gw1, const float* __restrict__ gb1,
    const float* __restrict__ gw2, const float* __restrict__ gb2,
    const float* __restrict__ pw1, const float* __restrict__ pb1,
    const float* __restrict__ pw2, const float* __restrict__ pb2,
    const float* __restrict__ pz0_mean, const float* __restrict__ pz0_logstd,
    const float* __restrict__ tabs,
    int* __restrict__ ctr, float* __restrict__ partA, float* __restrict__ partB,
    float* __restrict__ out)
{
  const int tid = threadIdx.x;
  const int b   = blockIdx.x * 64 + tid;

  const float2* et2  = (const float2*)(tabs + ET2_OFF);
  const float4* hgp4 = (const float4*)(tabs + HGP_OFF);
  const float2* ft2  = (const float2*)(tabs + FT2_OFF);

  const float fb2s = fb2[0], hb2s = hb2[0], gb2s = gb2[0], pb2s = pb2[0];
  const float qw0 = qw[0], qw1 = qw[1], qb0 = qb[0], qb1 = qb[1];
  const float ns = noise_std[0];
  const float inv_ns = 1.0f / ns;
  const float nh_i2 = -0.5f * inv_ns * inv_ns;
  const float pm = pz0_mean[0], pls = pz0_logstd[0];

  auto einterp = [&](float x) {
    const float s = fmaf(x, XSF, XOF);
    const float sc = fminf(fmaxf(s, 0.0f), (float)(NXT - 1));
    const int i = (int)sc;
    const float fr = s - (float)i;
    const float2 e = et2[i];
    return fmaf(fr, e.y - e.x, e.x);
  };

  // exact fallbacks (rare: |z|>128 or c outside [-4,4])
  auto hgp_exact = [&](float z, float& hv, float& gv, float& pv) {
    float sh = 0.f, sg = 0.f, sp = 0.f;
    for (int j = 0; j < 64; ++j) {
      sh = fmaf(sp_precise(fmaf(z, hw1[j], hb1[j])), hw2[j], sh);
      sg = fmaf(sp_precise(fmaf(z, gw1[j], gb1[j])), gw2[j], sg);
      sp = fmaf(sp_precise(fmaf(z, pw1[j], pb1[j])), pw2[j], sp);
    }
    hv = sh + hb2s;
    gv = 1.0f / (1.0f + expf(-(sg + gb2s)));
    pv = sp + pb2s;
  };
  auto f_exact = [&](float z, float c) {
    float s = 0.f;
    for (int j = 0; j < 64; ++j)
      s = fmaf(sp_precise(fmaf(z, fw1[j], fmaf(c, fw1[64 + j], fb1[j]))), fw2[j], s);
    return s + fb2s;
  };

  // z index state
  int zi; float zf; bool zin;
  auto setz = [&](float z) {
    const float s = fmaf(z, ZSF, ZOF);
    zin = (s >= 0.0f) && (s <= (float)NZT);
    const float sc = fminf(fmaxf(s, 0.0f), (float)(NZT - 1));
    zi = (int)sc;
    zf = s - (float)zi;
  };

  // ---- prologue ----
  const float x0 = xs[b];
  float       x1 = xs[B_SZ + b];
  const float c0 = einterp(x0);
  float    c_cur = einterp(x1);
  const float qm  = fmaf(c0, qw0, qb0);
  const float qls = fmaf(c0, qw1, qb1);
  float z = fmaf(__expf(qls), eps0[b], qm);
  const float dqm = qm - pm;
  const float kl = (pls - qls)
                 + (__expf(2.0f * qls) + dqm * dqm) * (0.5f * __expf(-2.0f * pls))
                 - 0.5f;

  setz(z);
  float hv, gv, pv;
  if (zin) {
    const float4 a = hgp4[zi], bq = hgp4[zi + 1];
    hv = fmaf(zf, bq.x - a.x, a.x);
    gv = fmaf(zf, bq.y - a.y, a.y);
    pv = fmaf(zf, bq.z - a.z, a.z);
  } else {
    hgp_exact(z, hv, gv, pv);
  }
  float lp_sum; { const float d = x0 - pv; lp_sum = nh_i2 * d * d; }
  float dw_cur = dW[b];
  float lr_sum = 0.0f;
  float csx = fmaf(c_cur, CSF, COF);

  // ---- Euler-Maruyama scan ----
  for (int k = 0; k < T_SZ - 1; ++k) {
    const int   i2  = (k + 2 < T_SZ) ? (k + 2) : (T_SZ - 1);
    const float x2  = xs[i2 * B_SZ + b];
    const float dwn = (k + 1 < T_SZ - 1) ? dW[(k + 1) * B_SZ + b] : 0.0f;
    const float dt  = ts[k + 1] - ts[k];
    const float sq  = SQRTF(dt);

    // f(z, c): bilinear from c-pair table (or exact fallback)
    float fv;
    if (zin && (csx >= 0.0f) && (csx <= (float)NCT)) {
      const float sc = fminf(csx, (float)(NCT - 1));
      const int ci = (int)sc;
      const float cf = csx - (float)ci;
      const float2 r0 = ft2[zi * NCT + ci];
      const float2 r1 = ft2[(zi + 1) * NCT + ci];
      const float fa = fmaf(cf, r0.y - r0.x, r0.x);
      const float fbv = fmaf(cf, r1.y - r1.x, r1.x);
      fv = fmaf(zf, fbv - fa, fa);
    } else {
      fv = f_exact(z, c_cur);
    }

    const float uu = (fv - hv) * RCPF(gv);
    lr_sum = fmaf((0.5f * dt) * uu, uu, lr_sum);
    z = fmaf(gv * dw_cur, sq, fmaf(fv, dt, z));

    // h,g (for next step) + p (for lp now) at the new z
    setz(z);
    if (zin) {
      const float4 a = hgp4[zi], bq = hgp4[zi + 1];
      hv = fmaf(zf, bq.x - a.x, a.x);
      gv = fmaf(zf, bq.y - a.y, a.y);
      pv = fmaf(zf, bq.z - a.z, a.z);
    } else {
      hgp_exact(z, hv, gv, pv);
    }
    const float d = x1 - pv;
    lp_sum = fmaf(nh_i2 * d, d, lp_sum);

    x1 = x2; c_cur = einterp(x2); csx = fmaf(c_cur, CSF, COF); dw_cur = dwn;
  }

  // ---- fused deterministic reduction ----
  __shared__ float la[64], lb[64];
  __shared__ int lastflag;
  la[tid] = lp_sum; lb[tid] = kl + lr_sum;
  __syncthreads();
  for (int s = 32; s > 0; s >>= 1) {
    if (tid < s) { la[tid] += la[tid + s]; lb[tid] += lb[tid + s]; }
    __syncthreads();
  }
  if (tid == 0) {
    partA[blockIdx.x] = la[0]; partB[blockIdx.x] = lb[0];
    __threadfence();
    lastflag = (atomicAdd(ctr, 1) == NBLK - 1) ? 1 : 0;
  }
  __syncthreads();
  if (lastflag) {
    __threadfence();
    float sa = partA[tid] + partA[tid + 64];
    float sb = partB[tid] + partB[tid + 64];
    la[tid] = sa; lb[tid] = sb;
    __syncthreads();
    for (int s = 32; s > 0; s >>= 1) {
      if (tid < s) { la[tid] += la[tid + s]; lb[tid] += lb[tid + s]; }
      __syncthreads();
    }
    if (tid == 0) {
      out[0] = la[0] / (float)B_SZ
             + (float)T_SZ * (-__logf(ns) - 0.9189385332046727f);
      out[1] = lb[0] / (float)B_SZ;
    }
  }
}

extern "C" void kernel_launch(void* const* d_in, const int* in_sizes, int n_in,
                              void* d_out, int out_size, void* d_ws, size_t ws_size,
                              hipStream_t stream) {
  const float* xs        = (const float*)d_in[0];
  const float* ts        = (const float*)d_in[1];
  const float* noise_std = (const float*)d_in[2];
  const float* eps0      = (const float*)d_in[3];
  const float* dW        = (const float*)d_in[4];
  const float* ew1 = (const float*)d_in[5];
  const float* eb1 = (const float*)d_in[6];
  const float* ew2 = (const float*)d_in[7];
  const float* eb2 = (const float*)d_in[8];
  const float* qw  = (const float*)d_in[9];
  const float* qb  = (const float*)d_in[10];
  const float* fw1 = (const float*)d_in[11];
  const float* fb1 = (const float*)d_in[12];
  const float* fw2 = (const float*)d_in[13];
  const float* fb2 = (const float*)d_in[14];
  const float* hw1 = (const float*)d_in[15];
  const float* hb1 = (const float*)d_in[16];
  const float* hw2 = (const float*)d_in[17];
  const float* hb2 = (const float*)d_in[18];
  const float* gw1 = (const float*)d_in[19];
  const float* gb1 = (const float*)d_in[20];
  const float* gw2 = (const float*)d_in[21];
  const float* gb2 = (const float*)d_in[22];
  const float* pw1 = (const float*)d_in[23];
  const float* pb1 = (const float*)d_in[24];
  const float* pw2 = (const float*)d_in[25];
  const float* pb2 = (const float*)d_in[26];
  const float* pz0_mean   = (const float*)d_in[27];
  const float* pz0_logstd = (const float*)d_in[28];
  float* out = (float*)d_out;

  float* tabs  = (float*)d_ws;                    // [WS_FLOATS]
  int*   ctr   = (int*)(tabs + WS_FLOATS);        // [1]
  float* partA = tabs + WS_FLOATS + 4;            // [NBLK]
  float* partB = partA + NBLK;                    // [NBLK]

  build_tabs<<<(NBUILD + 255) / 256, 256, 0, stream>>>(
      ew1, eb1, ew2, eb2, fw1, fb1, fw2, fb2,
      hw1, hb1, hw2, hb2, gw1, gb1, gw2, gb2,
      pw1, pb1, pw2, pb2, tabs, ctr);

  sde_scan<<<NBLK, 64, 0, stream>>>(
      xs, ts, noise_std, eps0, dW, qw, qb,
      fw1, fb1, fw2, fb2, hw1, hb1, hw2, hb2,
      gw1, gb1, gw2, gb2, pw1, pb1, pw2, pb2,
      pz0_mean, pz0_logstd, tabs, ctr, partA, partB, out);
}